// Round 2
// baseline (3379.285 us; speedup 1.0000x reference)
//
#include <hip/hip_runtime.h>

#define DEVI __device__ __forceinline__

typedef __attribute__((ext_vector_type(8))) _Float16 halfx8;
typedef __attribute__((ext_vector_type(4))) short halfx4s;
typedef __attribute__((ext_vector_type(4))) float floatx4;

DEVI short f2h(float f) {
  _Float16 h = (_Float16)f;  // v_cvt_f16_f32, RNE
  return __builtin_bit_cast(short, h);
}

DEVI void gl_lds16(const void* g, void* l) {
  __builtin_amdgcn_global_load_lds(
      (const __attribute__((address_space(1))) void*)g,
      (__attribute__((address_space(3))) void*)l, 16, 0, 0);
}

// ---------------------------------------------------------------------------
// Generic NT GEMM: C[M,N] = scale * A[M,K] * B[N,K]^T (+ bias)
// A, B fp16 (K contiguous), fp32 accumulate. Tile 128x128, BK=32,
// 256 threads = 4 waves, each wave owns a 64x64 quadrant (4x4 MFMA frags).
// BIAS: 0 none, 1 per-row (M), 2 per-col (N). OutT: short (fp16) or float.
// Batch: z -> (zb = z/zdiv, zh = z%zdiv), pointer += zb*s0 + zh*s1.
// ---------------------------------------------------------------------------
template <typename OutT, int BIAS>
__global__ __launch_bounds__(256) void gemm_nt(
    const short* __restrict__ A, const short* __restrict__ B,
    OutT* __restrict__ C, const float* __restrict__ bias,
    int K, int lda, int ldb, int ldc, float scale,
    long long a_s0, long long a_s1, long long b_s0, long long b_s1,
    long long c_s0, long long c_s1, int zdiv) {
  const int z = blockIdx.z;
  const int zb = z / zdiv, zh = z % zdiv;
  A += zb * a_s0 + zh * a_s1;
  B += zb * b_s0 + zh * b_s1;
  C += zb * c_s0 + zh * c_s1;

  const int m0 = blockIdx.y * 128, n0 = blockIdx.x * 128;
  const int t = threadIdx.x;
  const int wave = t >> 6, lane = t & 63;
  const int wm = wave >> 1, wn = wave & 1;

  __shared__ short As[128 * 32];
  __shared__ short Bs[128 * 32];

  floatx4 acc[4][4] = {};

  // staging: chunk c = issue*256 + t covers row c/4, 16B col chunk c%4
  const char* ag = (const char*)(A + (long long)(m0 + (t >> 2)) * lda + (t & 3) * 8);
  const char* bg = (const char*)(B + (long long)(n0 + (t >> 2)) * ldb + (t & 3) * 8);
  const long long astep = (long long)lda * 2 * 64;  // 64 rows, bytes
  const long long bstep = (long long)ldb * 2 * 64;
  short* asl = As + t * 8;
  short* bsl = Bs + t * 8;

  const int a_off = (wm * 64 + (lane & 15)) * 32 + (lane >> 4) * 8;
  const int b_off = (wn * 64 + (lane & 15)) * 32 + (lane >> 4) * 8;

  for (int kt = 0; kt < K; kt += 32) {
    __syncthreads();
    gl_lds16(ag, asl);
    gl_lds16(ag + astep, asl + 2048);
    gl_lds16(bg, bsl);
    gl_lds16(bg + bstep, bsl + 2048);
    ag += 64;  // 32 fp16 = 64 bytes
    bg += 64;
    __syncthreads();
    halfx8 af[4], bfr[4];
#pragma unroll
    for (int i = 0; i < 4; i++) af[i] = *(const halfx8*)(As + a_off + i * 16 * 32);
#pragma unroll
    for (int j = 0; j < 4; j++) bfr[j] = *(const halfx8*)(Bs + b_off + j * 16 * 32);
#pragma unroll
    for (int i = 0; i < 4; i++)
#pragma unroll
      for (int j = 0; j < 4; j++)
        acc[i][j] =
            __builtin_amdgcn_mfma_f32_16x16x32_f16(af[i], bfr[j], acc[i][j], 0, 0, 0);
  }

  // epilogue: C/D layout col = lane&15, row = (lane>>4)*4 + reg
  const int lr = lane >> 4, lc = lane & 15;
#pragma unroll
  for (int i = 0; i < 4; i++) {
#pragma unroll
    for (int r = 0; r < 4; r++) {
      const int row = m0 + wm * 64 + i * 16 + lr * 4 + r;
      float bM = 0.f;
      if (BIAS == 1) bM = bias[row];
      const long long ro = (long long)row * ldc;
#pragma unroll
      for (int j = 0; j < 4; j++) {
        const int col = n0 + wn * 64 + j * 16 + lc;
        float v = acc[i][j][r] * scale;
        if (BIAS == 1) v += bM;
        if (BIAS == 2) v += bias[col];
        if constexpr (sizeof(OutT) == 2)
          C[ro + col] = f2h(v);
        else
          C[ro + col] = v;
      }
    }
  }
}

// fp32 -> fp16 elementwise cast, 4 elems/thread
__global__ void cast_f16(const float* __restrict__ in, short* __restrict__ out,
                         long long n) {
  long long i = ((long long)blockIdx.x * blockDim.x + threadIdx.x) * 4;
  if (i + 3 < n) {
    float4 v = *(const float4*)(in + i);
    halfx4s o;
    o[0] = f2h(v.x);
    o[1] = f2h(v.y);
    o[2] = f2h(v.z);
    o[3] = f2h(v.w);
    *(halfx4s*)(out + i) = o;
  }
}

// x[b][c][p] fp32 -> xT[b][p][c] fp16   (dim x dim per batch)
__global__ void transpose_cast(const float* __restrict__ x, short* __restrict__ xT,
                               int dim) {
  __shared__ float tile[64][65];
  const long long b = blockIdx.z;
  const float* xb = x + b * dim * (long long)dim;
  short* xTb = xT + b * dim * (long long)dim;
  const int c0 = blockIdx.y * 64, p0 = blockIdx.x * 64;
  const int tx = threadIdx.x & 63, ty = threadIdx.x >> 6;
#pragma unroll
  for (int i = 0; i < 64; i += 4)
    tile[ty + i][tx] = xb[(long long)(c0 + ty + i) * dim + p0 + tx];
  __syncthreads();
#pragma unroll
  for (int i = 0; i < 64; i += 4)
    xTb[(long long)(p0 + ty + i) * dim + c0 + tx] = f2h(tile[tx][ty + i]);
}

// row-wise softmax over 512 fp32 -> fp16; one 256-thread block per row
__global__ void softmax_rows(const float* __restrict__ S, short* __restrict__ P) {
  const long long row = blockIdx.x;
  const float* s = S + row * 512;
  const int t = threadIdx.x;
  float v0 = s[t], v1 = s[t + 256];
  float m = fmaxf(v0, v1);
  for (int o = 32; o; o >>= 1) m = fmaxf(m, __shfl_xor(m, o));
  __shared__ float red[4];
  const int wave = t >> 6, lane = t & 63;
  if (lane == 0) red[wave] = m;
  __syncthreads();
  m = fmaxf(fmaxf(red[0], red[1]), fmaxf(red[2], red[3]));
  float e0 = expf(v0 - m), e1 = expf(v1 - m);
  float sum = e0 + e1;
  for (int o = 32; o; o >>= 1) sum += __shfl_xor(sum, o);
  __syncthreads();
  if (lane == 0) red[wave] = sum;
  __syncthreads();
  sum = red[0] + red[1] + red[2] + red[3];
  const float inv = 1.0f / sum;
  short* p = P + row * 512;
  p[t] = f2h(e0 * inv);
  p[t + 256] = f2h(e1 * inv);
}

extern "C" void kernel_launch(void* const* d_in, const int* in_sizes, int n_in,
                              void* d_out, int out_size, void* d_ws, size_t ws_size,
                              hipStream_t stream) {
  const float* x    = (const float*)d_in[0];
  const float* Wqkv = (const float*)d_in[1];
  const float* bqkv = (const float*)d_in[2];
  const float* Wq   = (const float*)d_in[3];
  const float* bq   = (const float*)d_in[4];
  const float* Wk   = (const float*)d_in[5];
  const float* bk   = (const float*)d_in[6];
  const float* Wv   = (const float*)d_in[7];
  const float* bv   = (const float*)d_in[8];
  const float* Wout = (const float*)d_in[9];
  const float* bout = (const float*)d_in[10];
  float* out = (float*)d_out;

  const long long C = 4096, CPH = 512, P = 4096;

  size_t off = 0;
  auto alloc = [&](size_t bytes) -> char* {
    char* p = (char*)d_ws + off;
    off += (bytes + 255) & ~(size_t)255;
    return p;
  };
  short* Wqkv_b = (short*)alloc(3 * C * C * 2);   // reused as k2 after G1
  short* Wq_b   = (short*)alloc(C * C * 2);
  short* Wk_b   = (short*)alloc(C * C * 2);
  short* Wv_b   = (short*)alloc(C * C * 2);
  short* Wout_b = (short*)alloc(C * C * 2);
  short* xT     = (short*)alloc(2 * C * P * 2);   // reused as q2 after G1
  short* qkv    = (short*)alloc(2 * 3 * C * P * 2);
  short* v2T    = (short*)alloc(16 * C * CPH * 2);
  float* S      = (float*)alloc(16 * CPH * CPH * 4);
  short* Pm     = (short*)alloc(16 * CPH * CPH * 2);
  short* outT   = (short*)alloc(2 * C * P * 2);
  short* q2 = xT;
  short* k2 = Wqkv_b;
  if (off > ws_size) return;  // workspace too small: bail (will fail check loudly)

  // --- casts + transpose ---
  cast_f16<<<dim3((unsigned)(3 * C * C / 4 / 256)), 256, 0, stream>>>(Wqkv, Wqkv_b, 3 * C * C);
  cast_f16<<<dim3((unsigned)(C * C / 4 / 256)), 256, 0, stream>>>(Wq, Wq_b, C * C);
  cast_f16<<<dim3((unsigned)(C * C / 4 / 256)), 256, 0, stream>>>(Wk, Wk_b, C * C);
  cast_f16<<<dim3((unsigned)(C * C / 4 / 256)), 256, 0, stream>>>(Wv, Wv_b, C * C);
  cast_f16<<<dim3((unsigned)(C * C / 4 / 256)), 256, 0, stream>>>(Wout, Wout_b, C * C);
  transpose_cast<<<dim3(64, 64, 2), 256, 0, stream>>>(x, xT, 4096);

  // --- G1: qkv[b][o][p] = Wqkv . xT^T + bqkv  (M=12288,N=4096,K=4096, z=b) ---
  gemm_nt<short, 1><<<dim3(32, 96, 2), 256, 0, stream>>>(
      Wqkv_b, xT, qkv, bqkv, 4096, 4096, 4096, 4096, 1.f,
      0, 0, C * P, 0, 3 * C * P, 0, 1);

  // --- G2: q2[b][hc][m] = qkv_q . Wq^T + bq(col) ---
  gemm_nt<short, 2><<<dim3(32, 32, 2), 256, 0, stream>>>(
      qkv, Wq_b, q2, bq, 4096, 4096, 4096, 4096, 1.f,
      3 * C * P, 0, 0, 0, C * P, 0, 1);

  // --- G3: k2 = qkv_k . Wk^T + bk(col) ---
  gemm_nt<short, 2><<<dim3(32, 32, 2), 256, 0, stream>>>(
      qkv + C * P, Wk_b, k2, bk, 4096, 4096, 4096, 4096, 1.f,
      3 * C * P, 0, 0, 0, C * P, 0, 1);

  // --- G4: v2T[z][m][d] = Wv . v_slice^T + bv(row)  (M=4096,N=512,K=4096, z=b*8+h) ---
  gemm_nt<short, 1><<<dim3(4, 32, 16), 256, 0, stream>>>(
      Wv_b, qkv + 2 * C * P, v2T, bv, 4096, 4096, 4096, 512, 1.f,
      0, 0, 3 * C * P, CPH * P, 8 * C * CPH, C * CPH, 8);

  // --- G5: S[z][c][d] = 0.125 * q2_slice . k2_slice^T  (M=512,N=512,K=4096) ---
  gemm_nt<float, 0><<<dim3(4, 4, 16), 256, 0, stream>>>(
      q2, k2, S, nullptr, 4096, 4096, 4096, 512, 0.125f,
      C * P, CPH * P, C * P, CPH * P, 8 * CPH * CPH, CPH * CPH, 8);

  // --- softmax rows (16*512 rows of 512) ---
  softmax_rows<<<dim3(16 * 512), 256, 0, stream>>>(S, Pm);

  // --- G6: outT[b][m][h*512+c] = v2T_slice . P_slice^T  (M=4096,N=512,K=512) ---
  gemm_nt<short, 0><<<dim3(4, 32, 16), 256, 0, stream>>>(
      v2T, Pm, outT, nullptr, 512, 512, 512, 4096, 1.f,
      8 * C * CPH, C * CPH, 8 * CPH * CPH, CPH * CPH, C * P, 512, 8);

  // --- G7: out[b][o][p] = Wout . outT^T + bout(row)  (M=N=K=4096, fp32 out) ---
  gemm_nt<float, 1><<<dim3(32, 32, 2), 256, 0, stream>>>(
      Wout_b, outT, out, bout, 4096, 4096, 4096, 4096, 1.f,
      0, 0, C * P, 0, C * P, 0, 1);
}